// Round 5
// baseline (242.723 us; speedup 1.0000x reference)
//
#include <hip/hip_runtime.h>
#include <hip/hip_bf16.h>
#include <math.h>

#define LN_EPS 1e-5f

typedef __attribute__((ext_vector_type(8))) short bf16x8;
typedef __attribute__((ext_vector_type(4))) short bf16x4;
typedef __attribute__((ext_vector_type(8))) short short8;
typedef __attribute__((ext_vector_type(4))) float f32x4;
typedef unsigned short ushort_t;

__device__ __forceinline__ float silu_f(float x) {
    return x / (1.0f + __expf(-x));
}

__device__ __forceinline__ ushort_t f2bf(float f) {
    __hip_bfloat16 h = __float2bfloat16(f);
    return *reinterpret_cast<ushort_t*>(&h);
}

__device__ __forceinline__ float bf2f(ushort_t u) {
    __hip_bfloat16 h = *reinterpret_cast<__hip_bfloat16*>(&u);
    return __bfloat162float(h);
}

// pack two f32 -> one dword of 2 bf16 (lo = a, hi = b)
__device__ __forceinline__ unsigned pk2(float a, float b) {
#if defined(__has_builtin)
#if __has_builtin(__builtin_amdgcn_cvt_pk_bf16_f32)
    return __builtin_bit_cast(unsigned, __builtin_amdgcn_cvt_pk_bf16_f32(a, b));
#else
    return (((unsigned)f2bf(b)) << 16) | (unsigned)f2bf(a);
#endif
#else
    return (((unsigned)f2bf(b)) << 16) | (unsigned)f2bf(a);
#endif
}

// 16x16x16 bf16 MFMA (K=16): A regs 2, B regs 2, C/D 4.
__device__ __forceinline__ f32x4 mfma16(bf16x4 a, bf16x4 b, f32x4 c) {
#if defined(__has_builtin)
#if __has_builtin(__builtin_amdgcn_mfma_f32_16x16x16bf16_1k)
    return __builtin_amdgcn_mfma_f32_16x16x16bf16_1k(a, b, c, 0, 0, 0);
#elif __has_builtin(__builtin_amdgcn_mfma_f32_16x16x16_bf16)
    return __builtin_amdgcn_mfma_f32_16x16x16_bf16(a, b, c, 0, 0, 0);
#else
    f32x4 d = c;
    asm volatile("v_mfma_f32_16x16x16_bf16 %0, %1, %2, %0"
                 : "+v"(d) : "v"(a), "v"(b));
    return d;
#endif
#else
    f32x4 d = c;
    asm volatile("v_mfma_f32_16x16x16_bf16 %0, %1, %2, %0"
                 : "+v"(d) : "v"(a), "v"(b));
    return d;
#endif
}

// async global->LDS 16B per lane. lds must be wave-uniform; dst = lds + lane*16.
__device__ __forceinline__ void gld16(const void* g, void* lds) {
    __builtin_amdgcn_global_load_lds(
        (const __attribute__((address_space(1))) unsigned int*)g,
        (__attribute__((address_space(3))) unsigned int*)lds, 16, 0, 0);
}

// Block-wide reduction of (sum, sumsq). blockDim.x == 256 (4 waves of 64).
__device__ __forceinline__ float2 block_reduce2(float2 p, float2* sbuf) {
    #pragma unroll
    for (int off = 32; off > 0; off >>= 1) {
        p.x += __shfl_down(p.x, off, 64);
        p.y += __shfl_down(p.y, off, 64);
    }
    int lane = threadIdx.x & 63;
    int wid  = threadIdx.x >> 6;
    if (lane == 0) sbuf[wid] = p;
    __syncthreads();
    if (threadIdx.x == 0) {
        float2 r = sbuf[0];
        for (int i = 1; i < 4; ++i) { r.x += sbuf[i].x; r.y += sbuf[i].y; }
        sbuf[0] = r;
    }
    __syncthreads();
    return sbuf[0];
}

// ---------------------------------------------------------------------------
// LN (no affine) + SiLU, fp32 in -> bf16 out. One block per row of 1024.
// ---------------------------------------------------------------------------
__global__ __launch_bounds__(256) void ln_silu_kernel(
    const float* __restrict__ x, ushort_t* __restrict__ out)
{
    __shared__ float2 sbuf[4];
    const int C = 1024;
    int row = blockIdx.x;
    const float4* xr = (const float4*)(x + (size_t)row * C);
    float4 v = xr[threadIdx.x];
    float2 p;
    p.x = v.x + v.y + v.z + v.w;
    p.y = v.x*v.x + v.y*v.y + v.z*v.z + v.w*v.w;
    float2 s = block_reduce2(p, sbuf);
    float mean = s.x / (float)C;
    float var  = s.y / (float)C - mean * mean;
    float rstd = rsqrtf(var + LN_EPS);
    ushort4 y;
    y.x = f2bf(silu_f((v.x - mean) * rstd));
    y.y = f2bf(silu_f((v.y - mean) * rstd));
    y.z = f2bf(silu_f((v.z - mean) * rstd));
    y.w = f2bf(silu_f((v.w - mean) * rstd));
    ((ushort4*)(out + (size_t)row * C))[threadIdx.x] = y;
}

// ---------------------------------------------------------------------------
// Affine LN in place on bf16 rows of 1024, then scale.
// ---------------------------------------------------------------------------
__global__ __launch_bounds__(256) void ln_affine_bf16(
    ushort_t* __restrict__ q, const float* __restrict__ g,
    const float* __restrict__ be, float scale)
{
    __shared__ float2 sbuf[4];
    const int C = 1024;
    int row = blockIdx.x;
    ushort4 u = ((ushort4*)(q + (size_t)row * C))[threadIdx.x];
    float v0 = bf2f(u.x), v1 = bf2f(u.y), v2 = bf2f(u.z), v3 = bf2f(u.w);
    float2 p;
    p.x = v0 + v1 + v2 + v3;
    p.y = v0*v0 + v1*v1 + v2*v2 + v3*v3;
    float2 s = block_reduce2(p, sbuf);
    float mean = s.x / (float)C;
    float var  = s.y / (float)C - mean * mean;
    float rstd = rsqrtf(var + LN_EPS);
    float4 gv = ((const float4*)g)[threadIdx.x];
    float4 bv = ((const float4*)be)[threadIdx.x];
    ushort4 y;
    y.x = f2bf(((v0 - mean) * rstd * gv.x + bv.x) * scale);
    y.y = f2bf(((v1 - mean) * rstd * gv.y + bv.y) * scale);
    y.z = f2bf(((v2 - mean) * rstd * gv.z + bv.z) * scale);
    y.w = f2bf(((v3 - mean) * rstd * gv.w + bv.w) * scale);
    ((ushort4*)(q + (size_t)row * C))[threadIdx.x] = y;
}

// ---------------------------------------------------------------------------
// Transpose 4 fp32 weight matrices [1024][1024] -> bf16 [N][K] (W^T).
// ---------------------------------------------------------------------------
struct W4 { const float* p[4]; };

__global__ __launch_bounds__(256) void transpose_w(W4 w, ushort_t* __restrict__ outbase)
{
    __shared__ float Ls[64][65];
    int z = blockIdx.z;
    const float* in = w.p[z];
    ushort_t* out = outbase + (size_t)z * 1024 * 1024;
    int r0 = blockIdx.y * 64, c0 = blockIdx.x * 64;
    int t = threadIdx.x, r = t >> 2, j = (t & 3) * 16;
    #pragma unroll
    for (int i = 0; i < 4; ++i) {
        float4 v = *(const float4*)(in + (size_t)(r0 + r) * 1024 + c0 + j + i * 4);
        Ls[r][j + i*4 + 0] = v.x;
        Ls[r][j + i*4 + 1] = v.y;
        Ls[r][j + i*4 + 2] = v.z;
        Ls[r][j + i*4 + 3] = v.w;
    }
    __syncthreads();
    __align__(16) ushort_t tmp[16];
    #pragma unroll
    for (int i = 0; i < 16; ++i) tmp[i] = f2bf(Ls[j + i][r]);
    ushort_t* op = out + (size_t)(c0 + r) * 1024 + r0 + j;
    *(short8*)(op)     = *(short8*)(tmp);
    *(short8*)(op + 8) = *(short8*)(tmp + 8);
}

// ---------------------------------------------------------------------------
// bf16 MFMA GEMM: C[M,N] = A[M,K] @ Bt[N,K]^T + bias.
// BM x 128 tile, BK=64, 256 threads (4 waves, 2x2), 16x16x32 MFMA.
// global_load_lds staging with XOR chunk swizzle. z-grid selects weight/bias
// (fused QKV). z==2 (V) writes V^T directly in permuted-key layout
// (pos = 32w+8q+4tau+r holds key 32w+16tau+4q+r), packed 4 tokens per uint2.
// ---------------------------------------------------------------------------
template<int BM, bool OUT_BF16>
__global__ __launch_bounds__(256) void gemm_mfma(
    const ushort_t* __restrict__ A, const ushort_t* __restrict__ Bt0,
    const float* __restrict__ b0, const float* __restrict__ b1,
    const float* __restrict__ b2, void* __restrict__ out0,
    ushort_t* __restrict__ vt_out,
    int M, int N, int K)
{
    constexpr int BK = 64;
    constexpr int MI = BM / 32;          // m-tiles of 16 per wave
    __shared__ ushort_t As[BM * BK];
    __shared__ ushort_t Bs[128 * BK];

    int z = blockIdx.z;
    const ushort_t* Bt = Bt0 + (size_t)z * N * K;
    const float* bias = (z == 0) ? b0 : (z == 1) ? b1 : b2;

    int t = threadIdx.x;
    int lane = t & 63, wv = t >> 6;
    int wr = wv >> 1, wc = wv & 1;
    int quad = lane >> 4, ln16 = lane & 15;

    int row0 = blockIdx.y * BM;
    int col0 = blockIdx.x * 128;

    const f32x4 zero4 = {0.f, 0.f, 0.f, 0.f};
    f32x4 acc[MI][4];
    #pragma unroll
    for (int i = 0; i < MI; ++i)
        #pragma unroll
        for (int j = 0; j < 4; ++j) acc[i][j] = zero4;

    for (int kt = 0; kt < K; kt += BK) {
        #pragma unroll
        for (int c = 0; c < BM / 32; ++c) {
            int idx = c * 256 + t;
            int r = idx >> 3, ch = idx & 7;
            int g = ch ^ (r & 7);
            gld16(A + (size_t)(row0 + r) * K + kt + g * 8,
                  As + (size_t)(c * 256 + wv * 64) * 8);
        }
        #pragma unroll
        for (int c = 0; c < 4; ++c) {
            int idx = c * 256 + t;
            int r = idx >> 3, ch = idx & 7;
            int g = ch ^ (r & 7);
            gld16(Bt + (size_t)(col0 + r) * K + kt + g * 8,
                  Bs + (size_t)(c * 256 + wv * 64) * 8);
        }
        __syncthreads();
        #pragma unroll
        for (int s = 0; s < 2; ++s) {
            bf16x8 af[MI], bf[4];
            int g = s * 4 + quad;
            #pragma unroll
            for (int i = 0; i < MI; ++i) {
                int m = wr * (BM / 2) + i * 16 + ln16;
                af[i] = *(const bf16x8*)(As + (size_t)(m * 8 + (g ^ (m & 7))) * 8);
            }
            #pragma unroll
            for (int j = 0; j < 4; ++j) {
                int n = wc * 64 + j * 16 + ln16;
                bf[j] = *(const bf16x8*)(Bs + (size_t)(n * 8 + (g ^ (n & 7))) * 8);
            }
            #pragma unroll
            for (int i = 0; i < MI; ++i)
                #pragma unroll
                for (int j = 0; j < 4; ++j)
                    acc[i][j] = __builtin_amdgcn_mfma_f32_16x16x32_bf16(
                        af[i], bf[j], acc[i][j], 0, 0, 0);
        }
        __syncthreads();
    }

    if (OUT_BF16 && z == 2) {
        // V^T store: vt_out[b][channel][pos(token)], permuted-key layout.
        #pragma unroll
        for (int j = 0; j < 4; ++j) {
            int col = col0 + wc * 64 + j * 16 + ln16;   // channel
            float bv = bias[col];
            #pragma unroll
            for (int i = 0; i < MI; ++i) {
                int rowb = row0 + wr * (BM / 2) + i * 16 + quad * 4;  // token
                int bb = rowb >> 11;
                int n0 = rowb & 2047;
                int pos = (n0 & ~31) | ((n0 & 12) << 1) | ((n0 & 16) >> 2);
                uint2 uu;
                uu.x = pk2(acc[i][j][0] + bv, acc[i][j][1] + bv);
                uu.y = pk2(acc[i][j][2] + bv, acc[i][j][3] + bv);
                *(uint2*)(vt_out + ((size_t)bb * 1024 + col) * 2048 + pos) = uu;
            }
        }
    } else {
        #pragma unroll
        for (int j = 0; j < 4; ++j) {
            int col = col0 + wc * 64 + j * 16 + ln16;
            float bv = bias[col];
            #pragma unroll
            for (int i = 0; i < MI; ++i) {
                int rowb = row0 + wr * (BM / 2) + i * 16 + quad * 4;
                #pragma unroll
                for (int r = 0; r < 4; ++r) {
                    float val = acc[i][j][r] + bv;
                    if (OUT_BF16) {
                        ushort_t* out = (ushort_t*)out0 + (size_t)z * M * N;
                        out[(size_t)(rowb + r) * N + col] = f2bf(val);
                    } else {
                        float* out = (float*)out0;
                        out[(size_t)(rowb + r) * N + col] = val;
                    }
                }
            }
        }
    }
}

// ---------------------------------------------------------------------------
// MFMA flash attention, S^T formulation, register-resident P, STATIC softmax.
// Block = 256 thr (4 waves x 16 Q rows), 64 Q rows per block, one (b,h).
// Key tiles of 128. S^T = mfma_16x16x32(K_frag, Q_frag): lane owns q-row ln16.
// q pre-scaled by inner^-0.5 * log2(e); scores bounded (|s|<~3 in log2 space)
// so softmax uses fixed m=0: p = exp2(s), NO max tracking, NO alpha rescale,
// NO per-iter shuffles; l reduced cross-quad once at the end.
// PV: B = P straight from st regs (C-layout == B-operand layout of K=16 MFMA),
// A = V^T b128 frags from LDS (permuted-key layout: one 16B read serves two
// 16-key tiles). O accumulates transposed; epilogue fuses SiLU -> bf16.
// ---------------------------------------------------------------------------
__global__ __launch_bounds__(256, 4) void flash_mfma(
    const ushort_t* __restrict__ qb, const ushort_t* __restrict__ kb,
    const ushort_t* __restrict__ vT, ushort_t* __restrict__ ob)
{
    const int N = 2048, HD = 1024, D = 64, H = 16;
    const int KT = 128;
    __shared__ ushort_t Ks[128 * 64];      // [key][d], 8-chunk xor swizzle
    __shared__ ushort_t Vs[64 * 128];      // [d][perm-key], 16-chunk xor swizzle

    int t = threadIdx.x, lane = t & 63, wv = t >> 6;
    int quad = lane >> 4, ln16 = lane & 15;
    int qt = blockIdx.x, h = blockIdx.y, b = blockIdx.z;

    size_t qk_base = (size_t)b * N * HD + (size_t)h * D;
    size_t vt_base = (size_t)(b * H + h) * D * N;

    // Q fragment (B-operand, K=32) for this wave's 16 rows.
    bf16x8 qf[2];
    {
        const ushort_t* qp = qb + qk_base + (size_t)(qt * 64 + wv * 16 + ln16) * HD;
        qf[0] = *(const bf16x8*)(qp + quad * 8);
        qf[1] = *(const bf16x8*)(qp + 32 + quad * 8);
    }

    const f32x4 zero4 = {0.f, 0.f, 0.f, 0.f};
    f32x4 oacc[4];                         // O^T[d = mt*16+quad*4+r][qrow=ln16]
    #pragma unroll
    for (int j = 0; j < 4; ++j) oacc[j] = zero4;
    float lcur = 0.f;                      // partial sum (this quad's keys)

    for (int kt = 0; kt < N; kt += KT) {
        __syncthreads();   // all waves done with previous Ks/Vs
        #pragma unroll
        for (int c = 0; c < 4; ++c) {
            int idx = c * 256 + t;
            int r = idx >> 3, ch = idx & 7, g = ch ^ (r & 7);
            gld16(kb + qk_base + (size_t)(kt + r) * HD + g * 8,
                  Ks + (size_t)(c * 256 + wv * 64) * 8);
        }
        #pragma unroll
        for (int c = 0; c < 4; ++c) {
            int idx = c * 256 + t;
            int r = idx >> 4, ch = idx & 15, g = ch ^ (r & 15);
            gld16(vT + vt_base + (size_t)r * N + kt + g * 8,
                  Vs + (size_t)(c * 256 + wv * 64) * 8);
        }
        __syncthreads();

        // S^T = K @ Q^T : C-layout row=key(tile*16+quad*4+r), col=qrow(ln16).
        f32x4 st[8];
        #pragma unroll
        for (int j = 0; j < 8; ++j) st[j] = zero4;
        #pragma unroll
        for (int s = 0; s < 2; ++s) {
            int g = s * 4 + quad;
            #pragma unroll
            for (int j = 0; j < 8; ++j) {
                int n = j * 16 + ln16;
                bf16x8 kf = *(const bf16x8*)(Ks + ((size_t)n * 8 + (g ^ (n & 7))) * 8);
                st[j] = __builtin_amdgcn_mfma_f32_16x16x32_bf16(kf, qf[s], st[j], 0, 0, 0);
            }
        }

        // static softmax: p = exp2(s), accumulate partial l in-lane.
        #pragma unroll
        for (int j = 0; j < 8; ++j) {
            st[j][0] = exp2f(st[j][0]);
            st[j][1] = exp2f(st[j][1]);
            st[j][2] = exp2f(st[j][2]);
            st[j][3] = exp2f(st[j][3]);
            lcur += (st[j][0] + st[j][1]) + (st[j][2] + st[j][3]);
        }

        // O^T += V^T @ P : A = V^T b128 frag (two 16-key tiles per read),
        // B = P from st regs.
        #pragma unroll
        for (int w = 0; w < 4; ++w) {
            uint2 u0, u1;
            u0.x = pk2(st[2*w][0],   st[2*w][1]);
            u0.y = pk2(st[2*w][2],   st[2*w][3]);
            u1.x = pk2(st[2*w+1][0], st[2*w+1][1]);
            u1.y = pk2(st[2*w+1][2], st[2*w+1][3]);
            bf16x4 pf0 = __builtin_bit_cast(bf16x4, u0);
            bf16x4 pf1 = __builtin_bit_cast(bf16x4, u1);
            int lc = w * 4 + quad;
            #pragma unroll
            for (int mt = 0; mt < 4; ++mt) {
                int dd = mt * 16 + ln16;
                int phys = lc ^ ln16;
                bf16x8 vv = *(const bf16x8*)(Vs + (size_t)dd * 128 + phys * 8);
                bf16x4 vlo = __builtin_shufflevector(vv, vv, 0, 1, 2, 3);
                bf16x4 vhi = __builtin_shufflevector(vv, vv, 4, 5, 6, 7);
                oacc[mt] = mfma16(vlo, pf0, oacc[mt]);
                oacc[mt] = mfma16(vhi, pf1, oacc[mt]);
            }
        }
    }

    // final l: sum the 4 quads' partials (each quad saw 1/4 of the keys).
    lcur += __shfl_xor(lcur, 16, 64);
    lcur += __shfl_xor(lcur, 32, 64);

    // epilogue: O^T/l, SiLU, packed bf16 stores. Lane ln16 owns q-row ln16.
    float inv = 1.0f / lcur;
    size_t rowoff = qk_base + (size_t)(qt * 64 + wv * 16 + ln16) * HD;
    #pragma unroll
    for (int mt = 0; mt < 4; ++mt) {
        float o0 = silu_f(oacc[mt][0] * inv);
        float o1 = silu_f(oacc[mt][1] * inv);
        float o2 = silu_f(oacc[mt][2] * inv);
        float o3 = silu_f(oacc[mt][3] * inv);
        uint2 uu;
        uu.x = pk2(o0, o1);
        uu.y = pk2(o2, o3);
        *(uint2*)(ob + rowoff + mt * 16 + quad * 4) = uu;
    }
}

// ---------------------------------------------------------------------------
extern "C" void kernel_launch(void* const* d_in, const int* in_sizes, int n_in,
                              void* d_out, int out_size, void* d_ws, size_t ws_size,
                              hipStream_t stream) {
    const float* x    = (const float*)d_in[0];
    const float* w_q  = (const float*)d_in[1];
    const float* b_q  = (const float*)d_in[2];
    const float* w_k  = (const float*)d_in[3];
    const float* b_k  = (const float*)d_in[4];
    const float* w_v  = (const float*)d_in[5];
    const float* b_v  = (const float*)d_in[6];
    const float* g_q  = (const float*)d_in[7];
    const float* be_q = (const float*)d_in[8];
    const float* g_k  = (const float*)d_in[9];
    const float* be_k = (const float*)d_in[10];
    const float* w_o  = (const float*)d_in[11];
    const float* b_o  = (const float*)d_in[12];
    float* out = (float*)d_out;

    const int B = 2, N = 2048, C = 1024, H = 16, INNER = 1024;
    const int M = B * N;                       // 4096
    const size_t MC = (size_t)M * C;           // 4194304

    // ws layout (ushort elems): sx | qkv(3x, v slot unused) | vT | wT(4x)
    ushort_t* ws  = (ushort_t*)d_ws;
    ushort_t* sx  = ws;                        // [M][1024] bf16 (later reused as o)
    ushort_t* qkv = ws + MC;                   // [3][M][1024]
    ushort_t* vTp = ws + 4 * MC;               // [B][1024][2048] permuted keys
    ushort_t* wT  = ws + 5 * MC;               // [4][1024][1024]

    ushort_t* qbuf = qkv;
    ushort_t* kbuf = qkv + MC;
    ushort_t* obuf = sx;                       // sx dead after QKV GEMM

    // 1. weight transposes fp32 [K][N] -> bf16 [N][K]
    W4 w4; w4.p[0] = w_q; w4.p[1] = w_k; w4.p[2] = w_v; w4.p[3] = w_o;
    transpose_w<<<dim3(16, 16, 4), 256, 0, stream>>>(w4, wT);

    // 2. pre-norm + SiLU -> bf16
    ln_silu_kernel<<<M, 256, 0, stream>>>(x, sx);

    // 3. fused QKV GEMM (q/k bf16 rows; v written directly as permuted V^T)
    gemm_mfma<128, true><<<dim3(INNER / 128, M / 128, 3), 256, 0, stream>>>(
        sx, wT, b_q, b_k, b_v, qkv, vTp, M, INNER, C);

    // 4. q/k layernorms (bf16 in place); q scaled by inner^-0.5 * log2(e)
    //    (softmax computed in base 2 -> identical weights)
    ln_affine_bf16<<<M, 256, 0, stream>>>(qbuf, g_q, be_q, 0.03125f * 1.44269504f);
    ln_affine_bf16<<<M, 256, 0, stream>>>(kbuf, g_k, be_k, 1.0f);

    // 5. flash attention (writes silu(o) bf16 into obuf)
    flash_mfma<<<dim3(N / 64, H, B), 256, 0, stream>>>(qbuf, kbuf, vTp, obuf);

    // 6. final GEMM -> fp32 out
    gemm_mfma<64, false><<<dim3(C / 128, M / 64, 1), 256, 0, stream>>>(
        obuf, wT + (size_t)3 * 1024 * 1024, b_o, b_o, b_o, out, nullptr, M, C, INNER);
}

// Round 6
// 238.767 us; speedup vs baseline: 1.0166x; 1.0166x over previous
//
#include <hip/hip_runtime.h>
#include <hip/hip_bf16.h>
#include <math.h>

#define LN_EPS 1e-5f

typedef __attribute__((ext_vector_type(8))) short bf16x8;
typedef __attribute__((ext_vector_type(8))) short short8;
typedef __attribute__((ext_vector_type(4))) float f32x4;
typedef unsigned short ushort_t;

__device__ __forceinline__ float silu_f(float x) {
    return x / (1.0f + __expf(-x));
}

__device__ __forceinline__ ushort_t f2bf(float f) {
    __hip_bfloat16 h = __float2bfloat16(f);
    return *reinterpret_cast<ushort_t*>(&h);
}

__device__ __forceinline__ float bf2f(ushort_t u) {
    __hip_bfloat16 h = *reinterpret_cast<__hip_bfloat16*>(&u);
    return __bfloat162float(h);
}

// pack two f32 -> one dword of 2 bf16 (lo = a, hi = b)
__device__ __forceinline__ unsigned pk2(float a, float b) {
#if defined(__has_builtin)
#if __has_builtin(__builtin_amdgcn_cvt_pk_bf16_f32)
    return __builtin_bit_cast(unsigned, __builtin_amdgcn_cvt_pk_bf16_f32(a, b));
#else
    return (((unsigned)f2bf(b)) << 16) | (unsigned)f2bf(a);
#endif
#else
    return (((unsigned)f2bf(b)) << 16) | (unsigned)f2bf(a);
#endif
}

// async global->LDS 16B per lane. lds must be wave-uniform; dst = lds + lane*16.
__device__ __forceinline__ void gld16(const void* g, void* lds) {
    __builtin_amdgcn_global_load_lds(
        (const __attribute__((address_space(1))) unsigned int*)g,
        (__attribute__((address_space(3))) unsigned int*)lds, 16, 0, 0);
}

// Block-wide reduction of (sum, sumsq). blockDim.x == 256 (4 waves of 64).
__device__ __forceinline__ float2 block_reduce2(float2 p, float2* sbuf) {
    #pragma unroll
    for (int off = 32; off > 0; off >>= 1) {
        p.x += __shfl_down(p.x, off, 64);
        p.y += __shfl_down(p.y, off, 64);
    }
    int lane = threadIdx.x & 63;
    int wid  = threadIdx.x >> 6;
    if (lane == 0) sbuf[wid] = p;
    __syncthreads();
    if (threadIdx.x == 0) {
        float2 r = sbuf[0];
        for (int i = 1; i < 4; ++i) { r.x += sbuf[i].x; r.y += sbuf[i].y; }
        sbuf[0] = r;
    }
    __syncthreads();
    return sbuf[0];
}

// ---------------------------------------------------------------------------
// LN (no affine) + SiLU, fp32 in -> bf16 out. One block per row of 1024.
// ---------------------------------------------------------------------------
__global__ __launch_bounds__(256) void ln_silu_kernel(
    const float* __restrict__ x, ushort_t* __restrict__ out)
{
    __shared__ float2 sbuf[4];
    const int C = 1024;
    int row = blockIdx.x;
    const float4* xr = (const float4*)(x + (size_t)row * C);
    float4 v = xr[threadIdx.x];
    float2 p;
    p.x = v.x + v.y + v.z + v.w;
    p.y = v.x*v.x + v.y*v.y + v.z*v.z + v.w*v.w;
    float2 s = block_reduce2(p, sbuf);
    float mean = s.x / (float)C;
    float var  = s.y / (float)C - mean * mean;
    float rstd = rsqrtf(var + LN_EPS);
    ushort4 y;
    y.x = f2bf(silu_f((v.x - mean) * rstd));
    y.y = f2bf(silu_f((v.y - mean) * rstd));
    y.z = f2bf(silu_f((v.z - mean) * rstd));
    y.w = f2bf(silu_f((v.w - mean) * rstd));
    ((ushort4*)(out + (size_t)row * C))[threadIdx.x] = y;
}

// ---------------------------------------------------------------------------
// Affine LN in place on bf16 rows of 1024, then scale. grid.y selects q/k.
// ---------------------------------------------------------------------------
__global__ __launch_bounds__(256) void ln_affine_bf16(
    ushort_t* __restrict__ qk0, ushort_t* __restrict__ qk1,
    const float* __restrict__ g0, const float* __restrict__ be0,
    const float* __restrict__ g1, const float* __restrict__ be1,
    float scale0, float scale1)
{
    __shared__ float2 sbuf[4];
    const int C = 1024;
    int which = blockIdx.y;
    ushort_t* q = which ? qk1 : qk0;
    const float* g  = which ? g1  : g0;
    const float* be = which ? be1 : be0;
    float scale = which ? scale1 : scale0;
    int row = blockIdx.x;
    ushort4 u = ((ushort4*)(q + (size_t)row * C))[threadIdx.x];
    float v0 = bf2f(u.x), v1 = bf2f(u.y), v2 = bf2f(u.z), v3 = bf2f(u.w);
    float2 p;
    p.x = v0 + v1 + v2 + v3;
    p.y = v0*v0 + v1*v1 + v2*v2 + v3*v3;
    float2 s = block_reduce2(p, sbuf);
    float mean = s.x / (float)C;
    float var  = s.y / (float)C - mean * mean;
    float rstd = rsqrtf(var + LN_EPS);
    float4 gv = ((const float4*)g)[threadIdx.x];
    float4 bv = ((const float4*)be)[threadIdx.x];
    ushort4 y;
    y.x = f2bf(((v0 - mean) * rstd * gv.x + bv.x) * scale);
    y.y = f2bf(((v1 - mean) * rstd * gv.y + bv.y) * scale);
    y.z = f2bf(((v2 - mean) * rstd * gv.z + bv.z) * scale);
    y.w = f2bf(((v3 - mean) * rstd * gv.w + bv.w) * scale);
    ((ushort4*)(q + (size_t)row * C))[threadIdx.x] = y;
}

// ---------------------------------------------------------------------------
// Transpose 4 fp32 weight matrices [1024][1024] -> bf16 [N][K] (W^T).
// ---------------------------------------------------------------------------
struct W4 { const float* p[4]; };

__global__ __launch_bounds__(256) void transpose_w(W4 w, ushort_t* __restrict__ outbase)
{
    __shared__ float Ls[64][65];
    int z = blockIdx.z;
    const float* in = w.p[z];
    ushort_t* out = outbase + (size_t)z * 1024 * 1024;
    int r0 = blockIdx.y * 64, c0 = blockIdx.x * 64;
    int t = threadIdx.x, r = t >> 2, j = (t & 3) * 16;
    #pragma unroll
    for (int i = 0; i < 4; ++i) {
        float4 v = *(const float4*)(in + (size_t)(r0 + r) * 1024 + c0 + j + i * 4);
        Ls[r][j + i*4 + 0] = v.x;
        Ls[r][j + i*4 + 1] = v.y;
        Ls[r][j + i*4 + 2] = v.z;
        Ls[r][j + i*4 + 3] = v.w;
    }
    __syncthreads();
    __align__(16) ushort_t tmp[16];
    #pragma unroll
    for (int i = 0; i < 16; ++i) tmp[i] = f2bf(Ls[j + i][r]);
    ushort_t* op = out + (size_t)(c0 + r) * 1024 + r0 + j;
    *(short8*)(op)     = *(short8*)(tmp);
    *(short8*)(op + 8) = *(short8*)(tmp + 8);
}

// ---------------------------------------------------------------------------
// bf16 MFMA GEMM: C[M,N] = A[M,K] @ Bt[N,K]^T + bias.
// BM x 128 tile, BK=64, 256 threads (4 waves, 2x2), 16x16x32 MFMA.
// global_load_lds staging with XOR chunk swizzle. z-grid selects weight/bias
// (fused QKV). z==2 (V) writes V^T [b][channel][token] (natural order) via a
// wave-local LDS transpose -> coalesced 128B-segment stores.
// ---------------------------------------------------------------------------
template<int BM, bool OUT_BF16>
__global__ __launch_bounds__(256) void gemm_mfma(
    const ushort_t* __restrict__ A, const ushort_t* __restrict__ Bt0,
    const float* __restrict__ b0, const float* __restrict__ b1,
    const float* __restrict__ b2, void* __restrict__ out0,
    ushort_t* __restrict__ vt_out,
    int M, int N, int K)
{
    constexpr int BK = 64;
    constexpr int MI = BM / 32;          // m-tiles of 16 per wave
    __shared__ ushort_t Smem[(BM + 128) * BK];
    ushort_t* As = Smem;                 // [BM][64]
    ushort_t* Bs = Smem + BM * BK;       // [128][64]

    int z = blockIdx.z;
    const ushort_t* Bt = Bt0 + (size_t)z * N * K;
    const float* bias = (z == 0) ? b0 : (z == 1) ? b1 : b2;

    int t = threadIdx.x;
    int lane = t & 63, wv = t >> 6;
    int wr = wv >> 1, wc = wv & 1;
    int quad = lane >> 4, ln16 = lane & 15;

    int row0 = blockIdx.y * BM;
    int col0 = blockIdx.x * 128;

    const f32x4 zero4 = {0.f, 0.f, 0.f, 0.f};
    f32x4 acc[MI][4];
    #pragma unroll
    for (int i = 0; i < MI; ++i)
        #pragma unroll
        for (int j = 0; j < 4; ++j) acc[i][j] = zero4;

    for (int kt = 0; kt < K; kt += BK) {
        #pragma unroll
        for (int c = 0; c < BM / 32; ++c) {
            int idx = c * 256 + t;
            int r = idx >> 3, ch = idx & 7;
            int g = ch ^ (r & 7);
            gld16(A + (size_t)(row0 + r) * K + kt + g * 8,
                  As + (size_t)(c * 256 + wv * 64) * 8);
        }
        #pragma unroll
        for (int c = 0; c < 4; ++c) {
            int idx = c * 256 + t;
            int r = idx >> 3, ch = idx & 7;
            int g = ch ^ (r & 7);
            gld16(Bt + (size_t)(col0 + r) * K + kt + g * 8,
                  Bs + (size_t)(c * 256 + wv * 64) * 8);
        }
        __syncthreads();
        #pragma unroll
        for (int s = 0; s < 2; ++s) {
            bf16x8 af[MI], bf[4];
            int g = s * 4 + quad;
            #pragma unroll
            for (int i = 0; i < MI; ++i) {
                int m = wr * (BM / 2) + i * 16 + ln16;
                af[i] = *(const bf16x8*)(As + (size_t)(m * 8 + (g ^ (m & 7))) * 8);
            }
            #pragma unroll
            for (int j = 0; j < 4; ++j) {
                int n = wc * 64 + j * 16 + ln16;
                bf[j] = *(const bf16x8*)(Bs + (size_t)(n * 8 + (g ^ (n & 7))) * 8);
            }
            #pragma unroll
            for (int i = 0; i < MI; ++i)
                #pragma unroll
                for (int j = 0; j < 4; ++j)
                    acc[i][j] = __builtin_amdgcn_mfma_f32_16x16x32_bf16(
                        af[i], bf[j], acc[i][j], 0, 0, 0);
        }
        __syncthreads();
    }

    if (OUT_BF16 && z == 2 && BM == 128) {
        // V^T epilogue: transpose each wave's 64tok x 64ch tile via its own
        // 8KB LDS region (wave-local, no barrier; loop-exit barrier already
        // drained all LDS reads), then coalesced [channel][token] stores.
        ushort_t* tb = Smem + wv * 4096;           // 64 rows x 64 ushorts
        int tok0 = row0 + wr * 64;
        int chn0 = col0 + wc * 64;
        #pragma unroll
        for (int j = 0; j < 4; ++j) {
            int chl = j * 16 + ln16;
            float bv = bias[chn0 + chl];
            #pragma unroll
            for (int i = 0; i < MI; ++i) {
                uint2 uu;
                uu.x = pk2(acc[i][j][0] + bv, acc[i][j][1] + bv);
                uu.y = pk2(acc[i][j][2] + bv, acc[i][j][3] + bv);
                int hc = i * 4 + quad;                  // 8B half-chunk (tok/4)
                int phys = hc ^ ((chl & 7) << 1);       // keeps 16B pairs intact
                *(uint2*)(tb + chl * 64 + phys * 4) = uu;
            }
        }
        int bb2 = tok0 >> 11;
        int tokb = tok0 & 2047;
        #pragma unroll
        for (int p = 0; p < 8; ++p) {
            int chl = p * 8 + (lane >> 3);
            int tc  = lane & 7;
            int ptc = tc ^ (chl & 7);
            uint4 vvv = *(const uint4*)(tb + chl * 64 + ptc * 8);
            *(uint4*)(vt_out + ((size_t)bb2 * 1024 + chn0 + chl) * 2048 + tokb + tc * 8) = vvv;
        }
    } else {
        #pragma unroll
        for (int j = 0; j < 4; ++j) {
            int col = col0 + wc * 64 + j * 16 + ln16;
            float bv = bias[col];
            #pragma unroll
            for (int i = 0; i < MI; ++i) {
                int rowb = row0 + wr * (BM / 2) + i * 16 + quad * 4;
                #pragma unroll
                for (int r = 0; r < 4; ++r) {
                    float val = acc[i][j][r] + bv;
                    if (OUT_BF16) {
                        ushort_t* out = (ushort_t*)out0 + (size_t)z * M * N;
                        out[(size_t)(rowb + r) * N + col] = f2bf(val);
                    } else {
                        float* out = (float*)out0;
                        out[(size_t)(rowb + r) * N + col] = val;
                    }
                }
            }
        }
    }
}

// ---------------------------------------------------------------------------
// MFMA flash attention, S^T formulation, register-resident P, STATIC softmax,
// K=32 PV.
// Block = 256 thr (4 waves x 16 Q rows), 64 Q rows per block, one (b,h).
// Key tiles of 128. K rows staged with in-LDS permutation
// perm(16t+4q+r) = 8q+4t+r, so the concatenated score tiles (st[2w],st[2w+1])
// form the K=32 B-operand fragment over 8 consecutive NATURAL-order keys:
// PV = mfma_16x16x32(V^T_Afrag, P_regs) with V^T in natural [d][token] order.
// q pre-scaled by inner^-0.5 * log2(e); static m=0 softmax (scores bounded),
// l reduced cross-quad once at the end. O accumulates transposed
// (O^T[d][qrow=ln16]); epilogue fuses SiLU -> packed bf16.
// ---------------------------------------------------------------------------
__global__ __launch_bounds__(256, 4) void flash_mfma(
    const ushort_t* __restrict__ qb, const ushort_t* __restrict__ kb,
    const ushort_t* __restrict__ vT, ushort_t* __restrict__ ob)
{
    const int N = 2048, HD = 1024, D = 64, H = 16;
    const int KT = 128;
    __shared__ ushort_t Ks[128 * 64];      // [perm-pos][d], 8-chunk xor swizzle
    __shared__ ushort_t Vs[64 * 128];      // [d][token], 16-chunk xor swizzle

    int t = threadIdx.x, lane = t & 63, wv = t >> 6;
    int quad = lane >> 4, ln16 = lane & 15;
    int qt = blockIdx.x, h = blockIdx.y, b = blockIdx.z;

    size_t qk_base = (size_t)b * N * HD + (size_t)h * D;
    size_t vt_base = (size_t)(b * H + h) * D * N;

    // Q fragment (B-operand, K=32) for this wave's 16 rows.
    bf16x8 qf[2];
    {
        const ushort_t* qp = qb + qk_base + (size_t)(qt * 64 + wv * 16 + ln16) * HD;
        qf[0] = *(const bf16x8*)(qp + quad * 8);
        qf[1] = *(const bf16x8*)(qp + 32 + quad * 8);
    }

    const f32x4 zero4 = {0.f, 0.f, 0.f, 0.f};
    f32x4 oacc[4];                         // O^T[d = mt*16+quad*4+r][qrow=ln16]
    #pragma unroll
    for (int j = 0; j < 4; ++j) oacc[j] = zero4;
    float lcur = 0.f;                      // partial sum (this quad's keys)

    for (int kt = 0; kt < N; kt += KT) {
        __syncthreads();   // all waves done with previous Ks/Vs
        #pragma unroll
        for (int c = 0; c < 4; ++c) {
            int idx = c * 256 + t;
            int r = idx >> 3, ch = idx & 7, g = ch ^ (r & 7);
            // K row permutation: LDS pos r holds key perm(r)
            int pr = (r & ~31) | (((r >> 2) & 3) << 3) | (((r >> 4) & 1) << 2) | (r & 3);
            gld16(kb + qk_base + (size_t)(kt + pr) * HD + g * 8,
                  Ks + (size_t)(c * 256 + wv * 64) * 8);
        }
        #pragma unroll
        for (int c = 0; c < 4; ++c) {
            int idx = c * 256 + t;
            int r = idx >> 4, ch = idx & 15, g = ch ^ (r & 15);
            gld16(vT + vt_base + (size_t)r * N + kt + g * 8,
                  Vs + (size_t)(c * 256 + wv * 64) * 8);
        }
        __syncthreads();

        // S^T = K @ Q^T : C-layout row=pos(tile*16+quad*4+r), col=qrow(ln16).
        f32x4 st[8];
        #pragma unroll
        for (int j = 0; j < 8; ++j) st[j] = zero4;
        #pragma unroll
        for (int s = 0; s < 2; ++s) {
            int g = s * 4 + quad;
            #pragma unroll
            for (int j = 0; j < 8; ++j) {
                int n = j * 16 + ln16;
                bf16x8 kf = *(const bf16x8*)(Ks + ((size_t)n * 8 + (g ^ (n & 7))) * 8);
                st[j] = __builtin_amdgcn_mfma_f32_16x16x32_bf16(kf, qf[s], st[j], 0, 0, 0);
            }
        }

        // static softmax: p = exp2(s), accumulate partial l in-lane.
        #pragma unroll
        for (int j = 0; j < 8; ++j) {
            st[j][0] = exp2f(st[j][0]);
            st[j][1] = exp2f(st[j][1]);
            st[j][2] = exp2f(st[j][2]);
            st[j][3] = exp2f(st[j][3]);
            lcur += (st[j][0] + st[j][1]) + (st[j][2] + st[j][3]);
        }

        // O^T += V^T @ P, K=32: A = V^T b128 frag (8 consecutive keys),
        // B = P packed from (st[2w], st[2w+1]) = keys 32w + 8*quad + 0..7.
        #pragma unroll
        for (int w = 0; w < 4; ++w) {
            uint4 up;
            up.x = pk2(st[2*w][0],   st[2*w][1]);
            up.y = pk2(st[2*w][2],   st[2*w][3]);
            up.z = pk2(st[2*w+1][0], st[2*w+1][1]);
            up.w = pk2(st[2*w+1][2], st[2*w+1][3]);
            bf16x8 pf = __builtin_bit_cast(bf16x8, up);
            int lc = w * 4 + quad;
            #pragma unroll
            for (int mt = 0; mt < 4; ++mt) {
                int dd = mt * 16 + ln16;
                int phys = lc ^ ln16;      // dd & 15 == ln16
                bf16x8 vf = *(const bf16x8*)(Vs + (size_t)dd * 128 + phys * 8);
                oacc[mt] = __builtin_amdgcn_mfma_f32_16x16x32_bf16(vf, pf, oacc[mt], 0, 0, 0);
            }
        }
    }

    // final l: sum the 4 quads' partials (each quad saw 1/4 of the keys).
    lcur += __shfl_xor(lcur, 16, 64);
    lcur += __shfl_xor(lcur, 32, 64);

    // epilogue: O^T/l, SiLU, packed bf16 stores. Lane ln16 owns q-row ln16.
    float inv = 1.0f / lcur;
    size_t rowoff = qk_base + (size_t)(qt * 64 + wv * 16 + ln16) * HD;
    #pragma unroll
    for (int mt = 0; mt < 4; ++mt) {
        float o0 = silu_f(oacc[mt][0] * inv);
        float o1 = silu_f(oacc[mt][1] * inv);
        float o2 = silu_f(oacc[mt][2] * inv);
        float o3 = silu_f(oacc[mt][3] * inv);
        uint2 uu;
        uu.x = pk2(o0, o1);
        uu.y = pk2(o2, o3);
        *(uint2*)(ob + rowoff + mt * 16 + quad * 4) = uu;
    }
}

// ---------------------------------------------------------------------------
extern "C" void kernel_launch(void* const* d_in, const int* in_sizes, int n_in,
                              void* d_out, int out_size, void* d_ws, size_t ws_size,
                              hipStream_t stream) {
    const float* x    = (const float*)d_in[0];
    const float* w_q  = (const float*)d_in[1];
    const float* b_q  = (const float*)d_in[2];
    const float* w_k  = (const float*)d_in[3];
    const float* b_k  = (const float*)d_in[4];
    const float* w_v  = (const float*)d_in[5];
    const float* b_v  = (const float*)d_in[6];
    const float* g_q  = (const float*)d_in[7];
    const float* be_q = (const float*)d_in[8];
    const float* g_k  = (const float*)d_in[9];
    const float* be_k = (const float*)d_in[10];
    const float* w_o  = (const float*)d_in[11];
    const float* b_o  = (const float*)d_in[12];
    float* out = (float*)d_out;

    const int B = 2, N = 2048, C = 1024, H = 16, INNER = 1024;
    const int M = B * N;                       // 4096
    const size_t MC = (size_t)M * C;           // 4194304

    // ws layout (ushort elems): sx | qkv(3x, v slot unused) | vT | wT(4x)
    ushort_t* ws  = (ushort_t*)d_ws;
    ushort_t* sx  = ws;                        // [M][1024] bf16 (later reused as o)
    ushort_t* qkv = ws + MC;                   // [3][M][1024]
    ushort_t* vTp = ws + 4 * MC;               // [B][1024][2048] natural key order
    ushort_t* wT  = ws + 5 * MC;               // [4][1024][1024]

    ushort_t* qbuf = qkv;
    ushort_t* kbuf = qkv + MC;
    ushort_t* obuf = sx;                       // sx dead after QKV GEMM

    // 1. weight transposes fp32 [K][N] -> bf16 [N][K]
    W4 w4; w4.p[0] = w_q; w4.p[1] = w_k; w4.p[2] = w_v; w4.p[3] = w_o;
    transpose_w<<<dim3(16, 16, 4), 256, 0, stream>>>(w4, wT);

    // 2. pre-norm + SiLU -> bf16
    ln_silu_kernel<<<M, 256, 0, stream>>>(x, sx);

    // 3. fused QKV GEMM (q/k bf16 rows; v written as natural-order V^T)
    gemm_mfma<128, true><<<dim3(INNER / 128, M / 128, 3), 256, 0, stream>>>(
        sx, wT, b_q, b_k, b_v, qkv, vTp, M, INNER, C);

    // 4. q/k layernorms (bf16 in place); q scaled by inner^-0.5 * log2(e)
    //    (softmax computed in base 2 -> identical weights)
    ln_affine_bf16<<<dim3(M, 2), 256, 0, stream>>>(
        qbuf, kbuf, g_q, be_q, g_k, be_k, 0.03125f * 1.44269504f, 1.0f);

    // 5. flash attention (writes silu(o) bf16 into obuf)
    flash_mfma<<<dim3(N / 64, H, B), 256, 0, stream>>>(qbuf, kbuf, vTp, obuf);

    // 6. final GEMM -> fp32 out
    gemm_mfma<64, false><<<dim3(C / 128, M / 64, 1), 256, 0, stream>>>(
        obuf, wT + (size_t)3 * 1024 * 1024, b_o, b_o, b_o, out, nullptr, M, C, INNER);
}